// Round 2
// baseline (1069.801 us; speedup 1.0000x reference)
//
#include <hip/hip_runtime.h>

// Problem constants
#define BB   4
#define CC   128
#define DHW  32768           // 32*32*32
#define NN   131072          // BB*DHW
#define KK   1024

// Output layout (floats, concatenated in reference return order)
#define OUT_Q    0
#define OUT_LOSS 16777216
#define OUT_IDX  16777217
#define OUT_ESUM 16908289
#define OUT_EMB  16908545
// total out_size = 17039617

// Workspace layout (float offsets). Needs ~1.05 MB of ws.
#define WS_EMBT  0           // 131072 floats: embT[c][k]
#define WS_ENH   131072      // 1024 floats: 0.5*||e_k||^2
#define WS_LOSS  132096      // 1 float accumulator
#define WS_IDX   132100      // 131072 ints (16B aligned)

// ---------------------------------------------------------------------------
// prep: transpose embedding -> embT[C][K] (for quant gather), compute
// 0.5*||e||^2, zero loss accumulator.
// ---------------------------------------------------------------------------
__global__ __launch_bounds__(128) void prep_kernel(const float* __restrict__ emb,
                                                   float* __restrict__ embT,
                                                   float* __restrict__ enh,
                                                   float* __restrict__ loss_acc) {
    const int k = blockIdx.x;     // 0..1023
    const int c = threadIdx.x;    // 0..127
    float v = emb[k * CC + c];    // coalesced read
    embT[c * KK + k] = v;         // strided write; 512 KB total, L2 absorbs
    float s = v * v;
    #pragma unroll
    for (int o = 32; o > 0; o >>= 1) s += __shfl_down(s, o);
    __shared__ float part[2];
    if ((c & 63) == 0) part[c >> 6] = s;
    __syncthreads();
    if (c == 0) {
        enh[k] = 0.5f * (part[0] + part[1]);
        if (k == 0) *loss_acc = 0.0f;
    }
}

// ---------------------------------------------------------------------------
// argmin v2: one vector per lane, x[128] register-resident.
// e[k][c] is wave-uniform -> scalar path (s_load + v_fma with SGPR operand).
// No LDS, no barriers, no cross-lane reduction. key = 0.5||e||^2 - x.e
// preserves squared-distance ordering; strict < keeps first-occurrence ties.
// 4 independent FMA chains: 4-cyc dep latency hidden at 2-cyc issue.
// ---------------------------------------------------------------------------
__global__ __launch_bounds__(256, 2) void argmin_kernel(const float* __restrict__ x,
                                                        const float* __restrict__ emb,
                                                        const float* __restrict__ enh,
                                                        int* __restrict__ out_idx) {
    const int n   = blockIdx.x * 256 + threadIdx.x;
    const int b   = n >> 15;
    const int dhw = n & (DHW - 1);
    const float* __restrict__ xb = x + (size_t)b * CC * DHW + dhw;

    // Load this lane's vector: coalesced across lanes (stride-1 in dhw).
    float xr[CC];
    #pragma unroll
    for (int c = 0; c < CC; ++c) xr[c] = xb[(size_t)c * DHW];

    float best_val = 1e30f;
    int   best_idx = 0;

    for (int k = 0; k < KK; ++k) {
        const float* __restrict__ ek = emb + k * CC;  // wave-uniform address
        float a0 = 0.0f, a1 = 0.0f, a2 = 0.0f, a3 = 0.0f;
        #pragma unroll
        for (int c = 0; c < CC; c += 4) {
            a0 = fmaf(xr[c + 0], ek[c + 0], a0);
            a1 = fmaf(xr[c + 1], ek[c + 1], a1);
            a2 = fmaf(xr[c + 2], ek[c + 2], a2);
            a3 = fmaf(xr[c + 3], ek[c + 3], a3);
        }
        const float key = enh[k] - ((a0 + a1) + (a2 + a3));
        if (key < best_val) { best_val = key; best_idx = k; }
    }
    out_idx[n] = best_idx;
}

// ---------------------------------------------------------------------------
// quant: gather codes, write straight-through output, accumulate loss sum.
// out = in + (q - in), loss += (q - in)^2. Gather via embT rows (L1-hot 4KB).
// ---------------------------------------------------------------------------
__global__ __launch_bounds__(256) void quant_kernel(const float* __restrict__ x,
                                                    const float* __restrict__ embT,
                                                    const int* __restrict__ idx,
                                                    float* __restrict__ out,
                                                    float* __restrict__ loss_acc) {
    const int bid   = blockIdx.x;           // 0..511
    const int c0    = (bid & 3) * 32;
    const int chunk = bid >> 2;             // 0..127
    const int b     = chunk >> 5;           // 0..3
    const int dhw   = (chunk & 31) * 1024 + threadIdx.x * 4;
    const int n     = b * DHW + dhw;
    const int4 kk   = *(const int4*)(idx + n);
    const size_t base = (size_t)b * CC * DHW + dhw;

    float lacc = 0.0f;
    for (int c = c0; c < c0 + 32; ++c) {
        const float4 in4 = *(const float4*)(x + base + (size_t)c * DHW);
        const float* er  = embT + c * KK;
        const float d0 = er[kk.x] - in4.x;
        const float d1 = er[kk.y] - in4.y;
        const float d2 = er[kk.z] - in4.z;
        const float d3 = er[kk.w] - in4.w;
        float4 o4;
        o4.x = in4.x + d0; o4.y = in4.y + d1;
        o4.z = in4.z + d2; o4.w = in4.w + d3;
        *(float4*)(out + base + (size_t)c * DHW) = o4;
        lacc += d0 * d0 + d1 * d1 + d2 * d2 + d3 * d3;
    }
    #pragma unroll
    for (int o = 32; o > 0; o >>= 1) lacc += __shfl_down(lacc, o);
    __shared__ float part[4];
    if ((threadIdx.x & 63) == 0) part[threadIdx.x >> 6] = lacc;
    __syncthreads();
    if (threadIdx.x == 0)
        atomicAdd(loss_acc, part[0] + part[1] + part[2] + part[3]);
}

// ---------------------------------------------------------------------------
// tail: indices as float, embedding copy, encodings_sum zeros, loss finalize
// ---------------------------------------------------------------------------
__global__ __launch_bounds__(256) void tail_kernel(const int* __restrict__ idx,
                                                   const float* __restrict__ emb,
                                                   const float* __restrict__ loss_acc,
                                                   float* __restrict__ out) {
    const int g = blockIdx.x * 256 + threadIdx.x;
    if (g < NN) {
        out[OUT_IDX + g] = (float)idx[g];
    } else if (g < 2 * NN) {
        out[OUT_EMB + (g - NN)] = emb[g - NN];
    } else if (g < 2 * NN + 256) {
        out[OUT_ESUM + (g - 2 * NN)] = 0.0f;
    } else if (g == 2 * NN + 256) {
        // loss = 0.25 * mean((q - x)^2) * 10 = 2.5 * sum / numel
        out[OUT_LOSS] = 2.5f * (*loss_acc) / 16777216.0f;
    }
}

extern "C" void kernel_launch(void* const* d_in, const int* in_sizes, int n_in,
                              void* d_out, int out_size, void* d_ws, size_t ws_size,
                              hipStream_t stream) {
    const float* x   = (const float*)d_in[0];   // [4,128,32,32,32] fp32
    const float* emb = (const float*)d_in[1];   // [1024,128] fp32
    float* out = (float*)d_out;
    float* ws  = (float*)d_ws;

    float* embT     = ws + WS_EMBT;
    float* enh      = ws + WS_ENH;
    float* loss_acc = ws + WS_LOSS;
    int*   idx      = (int*)(ws + WS_IDX);

    prep_kernel<<<KK, 128, 0, stream>>>(emb, embT, enh, loss_acc);
    argmin_kernel<<<NN / 256, 256, 0, stream>>>(x, emb, enh, idx);
    quant_kernel<<<512, 256, 0, stream>>>(x, embT, idx, out, loss_acc);
    tail_kernel<<<(2 * NN + 256 + 256) / 256 + 1, 256, 0, stream>>>(idx, emb, loss_acc, out);
}

// Round 3
// 328.669 us; speedup vs baseline: 3.2550x; 3.2550x over previous
//
#include <hip/hip_runtime.h>

// Problem constants
#define BB   4
#define CC   128
#define DHW  32768           // 32*32*32
#define NN   131072          // BB*DHW
#define KK   1024

// Output layout (floats, concatenated in reference return order)
#define OUT_Q    0
#define OUT_LOSS 16777216
#define OUT_IDX  16777217
#define OUT_ESUM 16908289
#define OUT_EMB  16908545

// Workspace layout (float offsets). Total ~2.1 MB.
#define WS_EMBT  0           // 131072 floats: embT[c][k]  (for quant gather)
#define WS_ENH   131072      // 1024 floats: 0.5*||e_k||^2
#define WS_LOSS  132096      // 1 float loss accumulator
#define WS_CNT   132097      // 1 int rescue counter
#define WS_IDX   132100      // 131072 ints (16B aligned)
#define WS_LIST  263172      // 131072 ints rescue list
#define WS_EMBF  394244      // 131072 floats: bf16 hi/lo B-fragments

#define EPS_GAP  0.0078125f  // 2^-7: flag near-ties for exact fp32 rescore

typedef __attribute__((ext_vector_type(8))) short  short8;   // 8 x bf16
typedef __attribute__((ext_vector_type(4))) float  f32x4;

// round-to-nearest-even fp32 -> bf16 (no NaN handling; inputs are finite)
__device__ inline unsigned short f2bf(float f) {
    unsigned u = __float_as_uint(f);
    return (unsigned short)((u + 0x7FFFu + ((u >> 16) & 1u)) >> 16);
}
__device__ inline float bf2f(unsigned short h) {
    return __uint_as_float(((unsigned)h) << 16);
}

// ---------------------------------------------------------------------------
// prep: transpose embedding -> embT[C][K], compute 0.5*||e||^2,
// zero loss + rescue counter.
// ---------------------------------------------------------------------------
__global__ __launch_bounds__(128) void prep_kernel(const float* __restrict__ emb,
                                                   float* __restrict__ embT,
                                                   float* __restrict__ enh,
                                                   float* __restrict__ loss_acc,
                                                   int* __restrict__ cnt) {
    const int k = blockIdx.x;     // 0..1023
    const int c = threadIdx.x;    // 0..127
    float v = emb[k * CC + c];
    embT[c * KK + k] = v;
    float s = v * v;
    #pragma unroll
    for (int o = 32; o > 0; o >>= 1) s += __shfl_down(s, o);
    __shared__ float part[2];
    if ((c & 63) == 0) part[c >> 6] = s;
    __syncthreads();
    if (c == 0) {
        enh[k] = 0.5f * (part[0] + part[1]);
        if (k == 0) { *loss_acc = 0.0f; *cnt = 0; }
    }
}

// ---------------------------------------------------------------------------
// prep_emb: build B-operand fragments (bf16 hi/lo) for mfma_f32_16x16x32_bf16.
// B[k][n] = e[code = cc*16 + n][c = kc*32 + k]; per-lane: n = lane&15,
// k = (lane>>4)*8 + j, j=0..7. One float4 (8 bf16) per (cc,kc,prec,lane).
// Layout: embF4[cc*512 + (kc*2+prec)*64 + lane]
// ---------------------------------------------------------------------------
__global__ __launch_bounds__(256) void prep_emb_kernel(const float* __restrict__ emb,
                                                       short8* __restrict__ embF) {
    const int cc   = blockIdx.x;        // 0..63
    const int kc   = threadIdx.x >> 6;  // 0..3
    const int lane = threadIdx.x & 63;
    const int code = cc * 16 + (lane & 15);
    const int cb   = kc * 32 + (lane >> 4) * 8;
    const float* src = emb + code * CC + cb;
    short8 h, l;
    #pragma unroll
    for (int j = 0; j < 8; ++j) {
        float v = src[j];
        unsigned short hb = f2bf(v);
        float lo = v - bf2f(hb);
        h[j] = (short)hb;
        l[j] = (short)f2bf(lo);
    }
    embF[cc * 512 + (kc * 2 + 0) * 64 + lane] = h;
    embF[cc * 512 + (kc * 2 + 1) * 64 + lane] = l;
}

// ---------------------------------------------------------------------------
// argmin v3: split-bf16 MFMA. Wave owns 32 vectors (2 M-tiles of 16),
// A hi/lo fragments register-resident; sweeps all 1024 codes in chunks of 16
// staged block-wide in LDS. key = 0.5||e||^2 - x.e  (3-pass split dot).
// Tracks best-2 per vector; near-ties (gap < EPS) appended for exact rescore.
// ---------------------------------------------------------------------------
__global__ __launch_bounds__(256, 3) void argmin_kernel(const float* __restrict__ x,
                                                        const float4* __restrict__ embF4,
                                                        const float* __restrict__ enh,
                                                        int* __restrict__ out_idx,
                                                        int* __restrict__ cnt,
                                                        int* __restrict__ list) {
    __shared__ float4 bbuf[512];  // 8 KB: one 16-code chunk of B frags (hi+lo)

    const int t    = threadIdx.x;
    const int wave = t >> 6;
    const int lane = t & 63;
    const int quad = lane >> 4;
    const int l15  = lane & 15;

    const int n_wave = blockIdx.x * 128 + wave * 32;
    const int b      = n_wave >> 15;
    const int dhw0   = n_wave & (DHW - 1);
    const float* __restrict__ xb = x + (size_t)b * CC * DHW + dhw0;

    // Build A fragments: A[m=l15][k=quad*8+j], m = vec-in-tile, k = c-in-chunk.
    short8 a_hi[2][4], a_lo[2][4];
    #pragma unroll
    for (int tile = 0; tile < 2; ++tile) {
        const int voff = tile * 16 + l15;
        #pragma unroll
        for (int kc = 0; kc < 4; ++kc) {
            const int c0 = kc * 32 + quad * 8;
            #pragma unroll
            for (int j = 0; j < 8; ++j) {
                float v = xb[(size_t)(c0 + j) * DHW + voff];
                unsigned short hb = f2bf(v);
                float lo = v - bf2f(hb);
                a_hi[tile][kc][j] = (short)hb;
                a_lo[tile][kc][j] = (short)f2bf(lo);
            }
        }
    }

    float bv1[2][4], bv2[2][4];
    int   bi1[2][4];
    #pragma unroll
    for (int tile = 0; tile < 2; ++tile)
        #pragma unroll
        for (int r = 0; r < 4; ++r) { bv1[tile][r] = 1e30f; bv2[tile][r] = 1e30f; bi1[tile][r] = 0; }

    // prologue prefetch for cc=0
    float4 p0 = embF4[t];
    float4 p1 = embF4[256 + t];

    for (int cc = 0; cc < 64; ++cc) {
        bbuf[t] = p0;
        bbuf[256 + t] = p1;
        __syncthreads();
        if (cc < 63) {
            p0 = embF4[(cc + 1) * 512 + t];
            p1 = embF4[(cc + 1) * 512 + 256 + t];
        }

        const short8* bf = (const short8*)bbuf;
        f32x4 acc0 = {0.f, 0.f, 0.f, 0.f};
        f32x4 acc1 = {0.f, 0.f, 0.f, 0.f};
        #pragma unroll
        for (int kc = 0; kc < 4; ++kc) {
            const short8 bh = bf[(kc * 2 + 0) * 64 + lane];
            const short8 bl = bf[(kc * 2 + 1) * 64 + lane];
            acc0 = __builtin_amdgcn_mfma_f32_16x16x32_bf16(a_hi[0][kc], bh, acc0, 0, 0, 0);
            acc1 = __builtin_amdgcn_mfma_f32_16x16x32_bf16(a_hi[1][kc], bh, acc1, 0, 0, 0);
            acc0 = __builtin_amdgcn_mfma_f32_16x16x32_bf16(a_hi[0][kc], bl, acc0, 0, 0, 0);
            acc1 = __builtin_amdgcn_mfma_f32_16x16x32_bf16(a_hi[1][kc], bl, acc1, 0, 0, 0);
            acc0 = __builtin_amdgcn_mfma_f32_16x16x32_bf16(a_lo[0][kc], bh, acc0, 0, 0, 0);
            acc1 = __builtin_amdgcn_mfma_f32_16x16x32_bf16(a_lo[1][kc], bh, acc1, 0, 0, 0);
        }

        // C/D: col = lane&15 (code), row = quad*4 + reg (vec-in-tile)
        const int   code  = cc * 16 + l15;
        const float enh_v = enh[code];
        #pragma unroll
        for (int r = 0; r < 4; ++r) {
            float k0 = enh_v - acc0[r];
            if (k0 < bv1[0][r]) { bv2[0][r] = bv1[0][r]; bv1[0][r] = k0; bi1[0][r] = code; }
            else if (k0 < bv2[0][r]) bv2[0][r] = k0;
            float k1 = enh_v - acc1[r];
            if (k1 < bv1[1][r]) { bv2[1][r] = bv1[1][r]; bv1[1][r] = k1; bi1[1][r] = code; }
            else if (k1 < bv2[1][r]) bv2[1][r] = k1;
        }
        __syncthreads();  // done reading bbuf; safe to overwrite next iter
    }

    // Reduce across the 16 lanes of each quad-row group (cols of the tile).
    #pragma unroll
    for (int tile = 0; tile < 2; ++tile) {
        #pragma unroll
        for (int r = 0; r < 4; ++r) {
            float v1 = bv1[tile][r], v2 = bv2[tile][r];
            int   i1 = bi1[tile][r];
            #pragma unroll
            for (int off = 1; off < 16; off <<= 1) {
                float ov1 = __shfl_xor(v1, off, 64);
                int   oi1 = __shfl_xor(i1, off, 64);
                float ov2 = __shfl_xor(v2, off, 64);
                bool take = (ov1 < v1) || (ov1 == v1 && oi1 < i1);
                float loser = take ? v1 : ov1;
                if (take) { v1 = ov1; i1 = oi1; }
                v2 = fminf(fminf(v2, ov2), loser);
            }
            if (l15 == 0) {
                const int n = n_wave + tile * 16 + quad * 4 + r;
                out_idx[n] = i1;
                if (v2 - v1 < EPS_GAP) {
                    int pos = atomicAdd(cnt, 1);
                    list[pos] = n;
                }
            }
        }
    }
}

// ---------------------------------------------------------------------------
// rescue: exact fp32 argmin for flagged near-tie vectors.
// ---------------------------------------------------------------------------
__global__ __launch_bounds__(256) void rescue_kernel(const float* __restrict__ x,
                                                     const float* __restrict__ emb,
                                                     const float* __restrict__ enh,
                                                     const int* __restrict__ cnt,
                                                     const int* __restrict__ list,
                                                     int* __restrict__ out_idx) {
    __shared__ float xs[CC];
    __shared__ float rv[256];
    __shared__ int   ri[256];
    const int m = *cnt;
    for (int it = blockIdx.x; it < m; it += gridDim.x) {
        const int n   = list[it];
        const int b   = n >> 15;
        const int dhw = n & (DHW - 1);
        if (threadIdx.x < CC)
            xs[threadIdx.x] = x[(size_t)b * CC * DHW + (size_t)threadIdx.x * DHW + dhw];
        __syncthreads();
        float bv = 1e30f; int bi = 0;
        for (int k0 = 0; k0 < 4; ++k0) {
            const int k = k0 * 256 + threadIdx.x;
            const float* ek = emb + k * CC;
            float a0 = 0.f, a1 = 0.f, a2 = 0.f, a3 = 0.f;
            #pragma unroll
            for (int c = 0; c < CC; c += 4) {
                a0 = fmaf(xs[c + 0], ek[c + 0], a0);
                a1 = fmaf(xs[c + 1], ek[c + 1], a1);
                a2 = fmaf(xs[c + 2], ek[c + 2], a2);
                a3 = fmaf(xs[c + 3], ek[c + 3], a3);
            }
            const float key = enh[k] - ((a0 + a1) + (a2 + a3));
            if (key < bv || (key == bv && k < bi)) { bv = key; bi = k; }
        }
        rv[threadIdx.x] = bv; ri[threadIdx.x] = bi;
        __syncthreads();
        for (int s = 128; s > 0; s >>= 1) {
            if (threadIdx.x < s) {
                float ov = rv[threadIdx.x + s]; int oi = ri[threadIdx.x + s];
                if (ov < rv[threadIdx.x] ||
                    (ov == rv[threadIdx.x] && oi < ri[threadIdx.x])) {
                    rv[threadIdx.x] = ov; ri[threadIdx.x] = oi;
                }
            }
            __syncthreads();
        }
        if (threadIdx.x == 0) out_idx[n] = ri[0];
        __syncthreads();
    }
}

// ---------------------------------------------------------------------------
// quant: gather codes, write straight-through output, accumulate loss sum.
// ---------------------------------------------------------------------------
__global__ __launch_bounds__(256) void quant_kernel(const float* __restrict__ x,
                                                    const float* __restrict__ embT,
                                                    const int* __restrict__ idx,
                                                    float* __restrict__ out,
                                                    float* __restrict__ loss_acc) {
    const int bid   = blockIdx.x;           // 0..511
    const int c0    = (bid & 3) * 32;
    const int chunk = bid >> 2;             // 0..127
    const int b     = chunk >> 5;           // 0..3
    const int dhw   = (chunk & 31) * 1024 + threadIdx.x * 4;
    const int n     = b * DHW + dhw;
    const int4 kk   = *(const int4*)(idx + n);
    const size_t base = (size_t)b * CC * DHW + dhw;

    float lacc = 0.0f;
    for (int c = c0; c < c0 + 32; ++c) {
        const float4 in4 = *(const float4*)(x + base + (size_t)c * DHW);
        const float* er  = embT + c * KK;
        const float d0 = er[kk.x] - in4.x;
        const float d1 = er[kk.y] - in4.y;
        const float d2 = er[kk.z] - in4.z;
        const float d3 = er[kk.w] - in4.w;
        float4 o4;
        o4.x = in4.x + d0; o4.y = in4.y + d1;
        o4.z = in4.z + d2; o4.w = in4.w + d3;
        *(float4*)(out + base + (size_t)c * DHW) = o4;
        lacc += d0 * d0 + d1 * d1 + d2 * d2 + d3 * d3;
    }
    #pragma unroll
    for (int o = 32; o > 0; o >>= 1) lacc += __shfl_down(lacc, o);
    __shared__ float part[4];
    if ((threadIdx.x & 63) == 0) part[threadIdx.x >> 6] = lacc;
    __syncthreads();
    if (threadIdx.x == 0)
        atomicAdd(loss_acc, part[0] + part[1] + part[2] + part[3]);
}

// ---------------------------------------------------------------------------
// tail: indices as float, embedding copy, encodings_sum zeros, loss finalize
// ---------------------------------------------------------------------------
__global__ __launch_bounds__(256) void tail_kernel(const int* __restrict__ idx,
                                                   const float* __restrict__ emb,
                                                   const float* __restrict__ loss_acc,
                                                   float* __restrict__ out) {
    const int g = blockIdx.x * 256 + threadIdx.x;
    if (g < NN) {
        out[OUT_IDX + g] = (float)idx[g];
    } else if (g < 2 * NN) {
        out[OUT_EMB + (g - NN)] = emb[g - NN];
    } else if (g < 2 * NN + 256) {
        out[OUT_ESUM + (g - 2 * NN)] = 0.0f;
    } else if (g == 2 * NN + 256) {
        out[OUT_LOSS] = 2.5f * (*loss_acc) / 16777216.0f;
    }
}

extern "C" void kernel_launch(void* const* d_in, const int* in_sizes, int n_in,
                              void* d_out, int out_size, void* d_ws, size_t ws_size,
                              hipStream_t stream) {
    const float* x   = (const float*)d_in[0];   // [4,128,32,32,32] fp32
    const float* emb = (const float*)d_in[1];   // [1024,128] fp32
    float* out = (float*)d_out;
    float* ws  = (float*)d_ws;

    float*  embT     = ws + WS_EMBT;
    float*  enh      = ws + WS_ENH;
    float*  loss_acc = ws + WS_LOSS;
    int*    cnt      = (int*)(ws + WS_CNT);
    int*    idx      = (int*)(ws + WS_IDX);
    int*    list     = (int*)(ws + WS_LIST);
    float*  embF     = ws + WS_EMBF;

    prep_kernel<<<KK, 128, 0, stream>>>(emb, embT, enh, loss_acc, cnt);
    prep_emb_kernel<<<64, 256, 0, stream>>>(emb, (short8*)embF);
    argmin_kernel<<<NN / 128, 256, 0, stream>>>(x, (const float4*)embF, enh, idx, cnt, list);
    rescue_kernel<<<128, 256, 0, stream>>>(x, emb, enh, cnt, list, idx);
    quant_kernel<<<512, 256, 0, stream>>>(x, embT, idx, out, loss_acc);
    tail_kernel<<<(2 * NN + 256 + 256) / 256 + 1, 256, 0, stream>>>(idx, emb, loss_acc, out);
}